// Round 2
// baseline (135.216 us; speedup 1.0000x reference)
//
#include <hip/hip_runtime.h>
#include <math.h>

// All internal math in f64 so every intermediate is within ~1e-13 of any
// f64 evaluation order of the reference (spike thresholds are chaotic in f32).
//
// Workspace layout (bytes):
//  part  : double[16][64][448] = 3,670,016   (fc1 K-split partials)
//  smask : u64[64][100][8]     =   409,600   (layer-1 spike bitmasks)
//  a2    : double[640][100]    =   512,000
//  u2    : double[640][100]    =   512,000
//  csum  : double[100]         =       800
//  srm   : double[100]         =       800
//  rk    : double[32]          =       256
#define WS_PART   0
#define WS_SMASK  3670016
#define WS_A2     (WS_SMASK + 409600)
#define WS_U2     (WS_A2 + 512000)
#define WS_CSUM   (WS_U2 + 512000)
#define WS_SRM    (WS_CSUM + 800)
#define WS_RK     (WS_SRM + 800)

// ---------------------------------------------------------------------------
// Kernel 1: fc1 GEMM (K-split, f64 accumulate).  A = flat (64x3072),
// B = w1 (410x3072), contraction over k.  part[s][n][o] = partial dot over
// 192-wide k-range s.  64x64 output tile per block, 4x4 per thread.
// Block (0,0) thread 0 also emits the srm/csum/rk tables in f64 (exact
// reference formulas: t/10.0 division + exp()).
// ---------------------------------------------------------------------------
__global__ __launch_bounds__(256) void k_gemm1(const float* __restrict__ flat,
                                               const float* __restrict__ w1,
                                               double* __restrict__ part,
                                               double* __restrict__ csumT,
                                               double* __restrict__ srmT,
                                               double* __restrict__ rkT) {
    if (blockIdx.x == 0 && blockIdx.y == 0 && threadIdx.x == 0) {
        double acc = 0.0;
        for (int k = 0; k < 100; ++k) {
            double kd = (double)k;
            double s = (kd / 10.0) * exp(1.0 - kd / 10.0);
            srmT[k] = s;
            acc += s;
            csumT[k] = acc;
        }
        for (int j = 0; j < 32; ++j) {
            double td = (double)(j + 1);
            rkT[j] = -20.0 * td * exp(1.0 - td);   // -scaleRef*theta*(t)*e^(1-t)
        }
    }

    __shared__ double As[64][35];   // pad 35: b64 reads stay <=2-way conflicts
    __shared__ double Bs[64][35];
    const int obase = blockIdx.x * 64;   // 0..384
    const int kbase = blockIdx.y * 192;  // 16 splits * 192 = 3072
    const int tid   = threadIdx.x;
    const int ldrow = tid >> 3;          // 0..31
    const int ldc4  = tid & 7;           // 0..7 (float4 col within 32-wide K chunk)
    const int tn    = tid & 15;
    const int to    = tid >> 4;          // 0..15

    double acc[4][4];
#pragma unroll
    for (int r = 0; r < 4; ++r)
#pragma unroll
        for (int c = 0; c < 4; ++c) acc[r][c] = 0.0;

    const float4* A4 = (const float4*)flat;  // row stride 768 float4
    const float4* B4 = (const float4*)w1;

#pragma unroll 1
    for (int ch = 0; ch < 6; ++ch) {
        const int k04 = (kbase + ch * 32) >> 2;
#pragma unroll
        for (int r = 0; r < 2; ++r) {
            const int row = ldrow + 32 * r;
            float4 va = A4[row * 768 + k04 + ldc4];
            As[row][ldc4 * 4 + 0] = (double)va.x;
            As[row][ldc4 * 4 + 1] = (double)va.y;
            As[row][ldc4 * 4 + 2] = (double)va.z;
            As[row][ldc4 * 4 + 3] = (double)va.w;
            const int orow = obase + row;
            float4 vb = make_float4(0.f, 0.f, 0.f, 0.f);
            if (orow < 410) vb = B4[orow * 768 + k04 + ldc4];
            Bs[row][ldc4 * 4 + 0] = (double)vb.x;
            Bs[row][ldc4 * 4 + 1] = (double)vb.y;
            Bs[row][ldc4 * 4 + 2] = (double)vb.z;
            Bs[row][ldc4 * 4 + 3] = (double)vb.w;
        }
        __syncthreads();
#pragma unroll
        for (int k = 0; k < 32; ++k) {
            double a[4], b[4];
#pragma unroll
            for (int r = 0; r < 4; ++r) a[r] = As[tn + 16 * r][k];
#pragma unroll
            for (int c = 0; c < 4; ++c) b[c] = Bs[to + 16 * c][k];
#pragma unroll
            for (int r = 0; r < 4; ++r)
#pragma unroll
                for (int c = 0; c < 4; ++c)
                    acc[r][c] = fma(a[r], b[c], acc[r][c]);
        }
        __syncthreads();
    }

    double* prow = part + (size_t)blockIdx.y * (64 * 448);
#pragma unroll
    for (int r = 0; r < 4; ++r)
#pragma unroll
        for (int c = 0; c < 4; ++c)
            prow[(tn + 16 * r) * 448 + obase + to + 16 * c] = acc[r][c];
}

// ---------------------------------------------------------------------------
// Refractory ring buffer (f64): spike at t injects rk[j] at t+1+j (j=0..31).
// Slot (t&31) consumed at t, re-armed for t+32. All indices compile-time.
// ---------------------------------------------------------------------------

// Kernel 2: layer-1 spike sim. One thread per (n,f), f padded to 448 so each
// wave = one 64-bit ballot word. u[t] = a1 * csum[t] (f64; equals the conv
// to ~1e-13). Emits spike bitmasks.
__global__ __launch_bounds__(256) void k_sim1(const double* __restrict__ part,
                                              const double* __restrict__ csumT,
                                              const double* __restrict__ rkT,
                                              unsigned long long* __restrict__ smask) {
    __shared__ double Cs[100];
    if (threadIdx.x < 100) Cs[threadIdx.x] = csumT[threadIdx.x];
    __syncthreads();

    const int gid = blockIdx.x * 256 + threadIdx.x;  // 112*256 = 28672 = 64*448
    const int n = gid / 448;
    const int f = gid - n * 448;

    double a1 = 0.0;
    if (f < 410) {
#pragma unroll
        for (int s = 0; s < 16; ++s)
            a1 += part[((size_t)(s * 64 + n)) * 448 + f];
    }

    double rk[32];
#pragma unroll
    for (int j = 0; j < 32; ++j) rk[j] = rkT[j];
    double ring[32];
#pragma unroll
    for (int j = 0; j < 32; ++j) ring[j] = 0.0;

    unsigned long long* mrow = smask + (size_t)n * 800;  // [100][8]
    const int wv = f >> 6;
    const bool lane0 = (threadIdx.x & 63) == 0;

#define SIM1_STEP(T, SLOT)                                                    \
    {                                                                         \
        double u = a1 * Cs[(T)];                                              \
        double m = u + ring[(SLOT)];                                          \
        bool p = (m >= 10.0);                                                 \
        unsigned long long b = __ballot(p);                                   \
        if (lane0) mrow[(T)*8 + wv] = b;                                      \
        double s = p ? 1.0 : 0.0;                                             \
        ring[(SLOT)] = s * rk[31];                                            \
        _Pragma("unroll") for (int j = 0; j < 31; ++j)                        \
            ring[((SLOT) + 1 + j) & 31] = fma(s, rk[j], ring[((SLOT)+1+j) & 31]); \
    }

#pragma unroll 1
    for (int t0 = 0; t0 < 3; ++t0) {
        const int tb = t0 * 32;
#pragma unroll
        for (int tt = 0; tt < 32; ++tt) SIM1_STEP(tb + tt, tt)
    }
#pragma unroll
    for (int tt = 0; tt < 4; ++tt) SIM1_STEP(96 + tt, tt)
#undef SIM1_STEP
}

// ---------------------------------------------------------------------------
// Kernel 3: fc2 from spike bitmasks, f64 accumulate (order-insensitive).
// One thread per (n,o,t).
// ---------------------------------------------------------------------------
__global__ __launch_bounds__(256) void k_fc2(const unsigned long long* __restrict__ smask,
                                             const float* __restrict__ w2,
                                             double* __restrict__ a2) {
    const int gid = blockIdx.x * 256 + threadIdx.x;  // 250*256 = 64000
    const int t = gid % 100;
    const int row = gid / 100;   // n*10+o
    const int o = row % 10;
    const int n = row / 10;
    const unsigned long long* mrow = smask + ((size_t)n * 100 + t) * 8;
    const float* wrow = w2 + o * 410;
    double acc = 0.0;
#pragma unroll
    for (int seg = 0; seg < 7; ++seg) {
        const unsigned long long mword = mrow[seg];
        const int jmax = (seg < 6) ? 64 : 26;  // 6*64+26 = 410
        for (int j = 0; j < jmax; j += 2) {
            float2 w = *(const float2*)&wrow[seg * 64 + j];
            acc = fma((double)((mword >> j) & 1ull), (double)w.x, acc);
            acc = fma((double)((mword >> (j + 1)) & 1ull), (double)w.y, acc);
        }
    }
    a2[gid] = acc;
}

// ---------------------------------------------------------------------------
// Kernel 4: psp for layer 2 (true causal conv in f64).
// One thread per (n,o,t): u2[t] = sum_{k<=t} srm[k] * a2[t-k].
// ---------------------------------------------------------------------------
__global__ __launch_bounds__(256) void k_psp2(const double* __restrict__ a2,
                                              const double* __restrict__ srmT,
                                              double* __restrict__ u2) {
    __shared__ double Ss[100];
    if (threadIdx.x < 100) Ss[threadIdx.x] = srmT[threadIdx.x];
    __syncthreads();
    const int gid = blockIdx.x * 256 + threadIdx.x;  // 64000
    const int t = gid % 100;
    const int row = gid / 100;
    const double* arow = a2 + row * 100;
    double acc = 0.0;
    for (int k = 0; k <= t; ++k) acc = fma(Ss[k], arow[t - k], acc);
    u2[gid] = acc;
}

// ---------------------------------------------------------------------------
// Kernel 5: layer-2 spike sim (f64). One thread per (n,o) = 640. Output f32.
// ---------------------------------------------------------------------------
__global__ __launch_bounds__(64) void k_sim2(const double* __restrict__ u2,
                                             const double* __restrict__ rkT,
                                             float* __restrict__ out) {
    const int gid = blockIdx.x * 64 + threadIdx.x;  // 10*64 = 640
    const double* urow = u2 + (size_t)gid * 100;
    float* orow = out + (size_t)gid * 100;

    double rk[32];
#pragma unroll
    for (int j = 0; j < 32; ++j) rk[j] = rkT[j];
    double ring[32];
#pragma unroll
    for (int j = 0; j < 32; ++j) ring[j] = 0.0;

#define SIM2_STEP(T, SLOT)                                                    \
    {                                                                         \
        double m = urow[(T)] + ring[(SLOT)];                                  \
        bool p = (m >= 10.0);                                                 \
        double s = p ? 1.0 : 0.0;                                             \
        orow[(T)] = (float)s;                                                 \
        ring[(SLOT)] = s * rk[31];                                            \
        _Pragma("unroll") for (int j = 0; j < 31; ++j)                        \
            ring[((SLOT) + 1 + j) & 31] = fma(s, rk[j], ring[((SLOT)+1+j) & 31]); \
    }

#pragma unroll 1
    for (int t0 = 0; t0 < 3; ++t0) {
        const int tb = t0 * 32;
#pragma unroll
        for (int tt = 0; tt < 32; ++tt) SIM2_STEP(tb + tt, tt)
    }
#pragma unroll
    for (int tt = 0; tt < 4; ++tt) SIM2_STEP(96 + tt, tt)
#undef SIM2_STEP
}

// ---------------------------------------------------------------------------
extern "C" void kernel_launch(void* const* d_in, const int* in_sizes, int n_in,
                              void* d_out, int out_size, void* d_ws, size_t ws_size,
                              hipStream_t stream) {
    const float* input = (const float*)d_in[0];  // (64,3,32,32) == flat (64,3072)
    const float* w1    = (const float*)d_in[1];  // (410,3072)
    const float* w2    = (const float*)d_in[2];  // (10,410)
    float* out = (float*)d_out;                  // (64,10,100) f32

    char* ws = (char*)d_ws;
    double* part  = (double*)(ws + WS_PART);
    unsigned long long* smask = (unsigned long long*)(ws + WS_SMASK);
    double* a2    = (double*)(ws + WS_A2);
    double* u2    = (double*)(ws + WS_U2);
    double* csumT = (double*)(ws + WS_CSUM);
    double* srmT  = (double*)(ws + WS_SRM);
    double* rkT   = (double*)(ws + WS_RK);

    k_gemm1<<<dim3(7, 16), 256, 0, stream>>>(input, w1, part, csumT, srmT, rkT);
    k_sim1<<<112, 256, 0, stream>>>(part, csumT, rkT, smask);
    k_fc2<<<250, 256, 0, stream>>>(smask, w2, a2);
    k_psp2<<<250, 256, 0, stream>>>(a2, srmT, u2);
    k_sim2<<<10, 64, 0, stream>>>(u2, rkT, out);
}